// Round 1
// baseline (1099.232 us; speedup 1.0000x reference)
//
#include <hip/hip_runtime.h>

__device__ __forceinline__ float elu_f(float x) { return x > 0.f ? x : expm1f(x); }
__device__ __forceinline__ float lrelu_f(float x) { return x > 0.f ? x : 0.2f * x; }

// ---------------- CSR build ----------------
__global__ void deg_count_k(const int* __restrict__ src, const int* __restrict__ dst,
                            int E, int n, int* __restrict__ deg) {
  int e = blockIdx.x * blockDim.x + threadIdx.x;
  if (e < E) {
    atomicAdd(&deg[dst[e]], 1);
  } else if (e < E + n) {
    atomicAdd(&deg[e - E], 1);  // self loop
  }
}

__global__ void scan_rowptr_k(const int* __restrict__ deg, int* __restrict__ rowptr, int n) {
  __shared__ int sd[1024];
  __shared__ int running_s;
  int tid = threadIdx.x;
  if (tid == 0) { running_s = 0; rowptr[0] = 0; }
  __syncthreads();
  for (int base = 0; base < n; base += 1024) {
    int i = base + tid;
    int v = (i < n) ? deg[i] : 0;
    sd[tid] = v;
    __syncthreads();
    for (int off = 1; off < 1024; off <<= 1) {
      int t2 = (tid >= off) ? sd[tid - off] : 0;
      __syncthreads();
      sd[tid] += t2;
      __syncthreads();
    }
    int incl = sd[tid];
    int r0 = running_s;
    if (i < n) rowptr[i + 1] = r0 + incl;
    int tot = sd[1023];
    __syncthreads();
    if (tid == 0) running_s = r0 + tot;
    __syncthreads();
  }
}

__global__ void copy_int_k(const int* __restrict__ a, int* __restrict__ b, int n) {
  int i = blockIdx.x * blockDim.x + threadIdx.x;
  if (i < n) b[i] = a[i];
}

__global__ void scatter_k(const int* __restrict__ src, const int* __restrict__ dst,
                          int E, int n, int* __restrict__ cursor, int* __restrict__ col) {
  int e = blockIdx.x * blockDim.x + threadIdx.x;
  if (e < E) {
    int d = dst[e];
    int pos = atomicAdd(&cursor[d], 1);
    col[pos] = src[e];
  } else if (e < E + n) {
    int d = e - E;
    int pos = atomicAdd(&cursor[d], 1);
    col[pos] = d;  // self loop
  }
}

// ---------------- GEMM: C[n,ncols] = A[n,K] @ W[ncols,K]^T (+bias,+elu) ----------------
template <int BIAS, int ELU>
__global__ __launch_bounds__(256) void gemm_nt_k(const float* __restrict__ A,
                                                 const float* __restrict__ W,
                                                 const float* __restrict__ bias,
                                                 float* __restrict__ C,
                                                 int n, int K, int ncols) {
  __shared__ float As[64][33];
  __shared__ float Ws[64][33];
  const int t = threadIdx.x;
  const int tx = t & 15, ty = t >> 4;
  const int row0 = blockIdx.x * 64, col0 = blockIdx.y * 64;
  float acc[4][4] = {};
  for (int k0 = 0; k0 < K; k0 += 32) {
#pragma unroll
    for (int i = 0; i < 2; ++i) {
      int idx = t + i * 256;
      int r = idx >> 3;
      int c = (idx & 7) << 2;
      int gr = row0 + r;
      float4 av = make_float4(0.f, 0.f, 0.f, 0.f);
      if (gr < n) av = *reinterpret_cast<const float4*>(&A[(size_t)gr * K + k0 + c]);
      As[r][c] = av.x; As[r][c + 1] = av.y; As[r][c + 2] = av.z; As[r][c + 3] = av.w;
      float4 wv = *reinterpret_cast<const float4*>(&W[(size_t)(col0 + r) * K + k0 + c]);
      Ws[r][c] = wv.x; Ws[r][c + 1] = wv.y; Ws[r][c + 2] = wv.z; Ws[r][c + 3] = wv.w;
    }
    __syncthreads();
#pragma unroll
    for (int kk = 0; kk < 32; ++kk) {
      float a0 = As[ty * 4 + 0][kk], a1 = As[ty * 4 + 1][kk];
      float a2 = As[ty * 4 + 2][kk], a3 = As[ty * 4 + 3][kk];
      float b0 = Ws[tx * 4 + 0][kk], b1 = Ws[tx * 4 + 1][kk];
      float b2 = Ws[tx * 4 + 2][kk], b3 = Ws[tx * 4 + 3][kk];
      acc[0][0] += a0 * b0; acc[0][1] += a0 * b1; acc[0][2] += a0 * b2; acc[0][3] += a0 * b3;
      acc[1][0] += a1 * b0; acc[1][1] += a1 * b1; acc[1][2] += a1 * b2; acc[1][3] += a1 * b3;
      acc[2][0] += a2 * b0; acc[2][1] += a2 * b1; acc[2][2] += a2 * b2; acc[2][3] += a2 * b3;
      acc[3][0] += a3 * b0; acc[3][1] += a3 * b1; acc[3][2] += a3 * b2; acc[3][3] += a3 * b3;
    }
    __syncthreads();
  }
#pragma unroll
  for (int i = 0; i < 4; ++i) {
    int r = row0 + ty * 4 + i;
    if (r >= n) continue;
    int cc = col0 + tx * 4;
    float4 v;
    float* vp = &v.x;
#pragma unroll
    for (int j = 0; j < 4; ++j) {
      float o = acc[i][j];
      if (BIAS) o += bias[cc + j];
      if (ELU) o = elu_f(o);
      vp[j] = o;
    }
    *reinterpret_cast<float4*>(&C[(size_t)r * ncols + cc]) = v;
  }
}

// ---------------- attention scores: asrcN/adstN [n,4] ----------------
__global__ void attn_scores_k(const float* __restrict__ feat, const float* __restrict__ a_s,
                              const float* __restrict__ a_d, float* __restrict__ asrcN,
                              float* __restrict__ adstN, int n) {
  int wave = threadIdx.x >> 6, lane = threadIdx.x & 63;
  int node = blockIdx.x * 4 + wave;
  if (node >= n) return;
  float4 f = *reinterpret_cast<const float4*>(&feat[(size_t)node * 256 + lane * 4]);
  float4 as = *reinterpret_cast<const float4*>(&a_s[lane * 4]);
  float4 ad = *reinterpret_cast<const float4*>(&a_d[lane * 4]);
  float ps = f.x * as.x + f.y * as.y + f.z * as.z + f.w * as.w;
  float pd = f.x * ad.x + f.y * ad.y + f.z * ad.z + f.w * ad.w;
#pragma unroll
  for (int off = 1; off < 16; off <<= 1) {
    ps += __shfl_xor(ps, off);
    pd += __shfl_xor(pd, off);
  }
  if ((lane & 15) == 0) {
    int h = lane >> 4;
    asrcN[(size_t)node * 4 + h] = ps;
    adstN[(size_t)node * 4 + h] = pd;
  }
}

// ---------------- GAT aggregation (wave per node) ----------------
__global__ void gat_aggregate_k(const float* __restrict__ feat, const float* __restrict__ asrcN,
                                const float* __restrict__ adstN, const int* __restrict__ rowptr,
                                const int* __restrict__ col, float* __restrict__ out, int n) {
  int wave = threadIdx.x >> 6, lane = threadIdx.x & 63;
  int node = blockIdx.x * 4 + wave;
  if (node >= n) return;
  int h = lane >> 4;
  float adst_h = adstN[(size_t)node * 4 + h];
  int s0 = rowptr[node], s1 = rowptr[node + 1];
  float m = -3.4e38f;
  for (int e = s0; e < s1; ++e) {
    int s = col[e];
    m = fmaxf(m, lrelu_f(asrcN[(size_t)s * 4 + h] + adst_h));
  }
  float ax = 0.f, ay = 0.f, az = 0.f, aw = 0.f, den = 0.f;
  for (int e = s0; e < s1; ++e) {
    int s = col[e];
    float a = lrelu_f(asrcN[(size_t)s * 4 + h] + adst_h);
    float ex = expf(a - m);
    den += ex;
    float4 f = *reinterpret_cast<const float4*>(&feat[(size_t)s * 256 + lane * 4]);
    ax += ex * f.x; ay += ex * f.y; az += ex * f.z; aw += ex * f.w;
  }
  float inv = 1.f / (den + 1e-16f);
  float4 o = make_float4(ax * inv, ay * inv, az * inv, aw * inv);
  *reinterpret_cast<float4*>(&out[(size_t)node * 256 + lane * 4]) = o;
}

// ---------------- bias + LayerNorm(256) + ELU, in-place ----------------
__global__ void post_concat_k(float* __restrict__ io, const float* __restrict__ bias,
                              const float* __restrict__ g, const float* __restrict__ be, int n) {
  int wave = threadIdx.x >> 6, lane = threadIdx.x & 63;
  int node = blockIdx.x * 4 + wave;
  if (node >= n) return;
  float4 v = *reinterpret_cast<const float4*>(&io[(size_t)node * 256 + lane * 4]);
  float4 b = *reinterpret_cast<const float4*>(&bias[lane * 4]);
  v.x += b.x; v.y += b.y; v.z += b.z; v.w += b.w;
  float s = v.x + v.y + v.z + v.w;
#pragma unroll
  for (int off = 1; off < 64; off <<= 1) s += __shfl_xor(s, off);
  float mu = s * (1.f / 256.f);
  float dx = v.x - mu, dy = v.y - mu, dz = v.z - mu, dw = v.w - mu;
  float q = dx * dx + dy * dy + dz * dz + dw * dw;
#pragma unroll
  for (int off = 1; off < 64; off <<= 1) q += __shfl_xor(q, off);
  float inv = rsqrtf(q * (1.f / 256.f) + 1e-5f);
  float4 gg = *reinterpret_cast<const float4*>(&g[lane * 4]);
  float4 bb = *reinterpret_cast<const float4*>(&be[lane * 4]);
  float4 o;
  o.x = elu_f(dx * inv * gg.x + bb.x);
  o.y = elu_f(dy * inv * gg.y + bb.y);
  o.z = elu_f(dz * inv * gg.z + bb.z);
  o.w = elu_f(dw * inv * gg.w + bb.w);
  *reinterpret_cast<float4*>(&io[(size_t)node * 256 + lane * 4]) = o;
}

// ---------------- head-mean + bias + LayerNorm(64) + ELU ----------------
__global__ void post_mean_k(const float* __restrict__ in, const float* __restrict__ bias,
                            const float* __restrict__ g, const float* __restrict__ be,
                            float* __restrict__ out, int n) {
  int wave = threadIdx.x >> 6, lane = threadIdx.x & 63;
  int node = blockIdx.x * 4 + wave;
  if (node >= n) return;
  const float* r = &in[(size_t)node * 256];
  float v = 0.25f * (r[lane] + r[64 + lane] + r[128 + lane] + r[192 + lane]) + bias[lane];
  float s = v;
#pragma unroll
  for (int off = 1; off < 64; off <<= 1) s += __shfl_xor(s, off);
  float mu = s * (1.f / 64.f);
  float d = v - mu;
  float q = d * d;
#pragma unroll
  for (int off = 1; off < 64; off <<= 1) q += __shfl_xor(q, off);
  float inv = rsqrtf(q * (1.f / 64.f) + 1e-5f);
  out[(size_t)node * 64 + lane] = elu_f(d * inv * g[lane] + be[lane]);
}

// ---------------- value head: out[n,4] ----------------
__global__ void value_head_k(const float* __restrict__ hh, const float* __restrict__ vw1,
                             const float* __restrict__ vb1, const float* __restrict__ vw2,
                             const float* __restrict__ vb2, float* __restrict__ out, int n) {
  __shared__ float w1s[32 * 65];
  __shared__ float hs[4][64];
  __shared__ float vs[4][33];
  int tid = threadIdx.x;
  for (int i = tid; i < 2048; i += 256) w1s[(i >> 6) * 65 + (i & 63)] = vw1[i];
  int wave = tid >> 6, lane = tid & 63;
  int node = blockIdx.x * 4 + wave;
  int nc = node < n ? node : n - 1;
  hs[wave][lane] = hh[(size_t)nc * 64 + lane];
  __syncthreads();
  int j = lane & 31, half = lane >> 5;
  float p = 0.f;
#pragma unroll
  for (int c = 0; c < 32; ++c) p += hs[wave][half * 32 + c] * w1s[j * 65 + half * 32 + c];
  p += __shfl_xor(p, 32);
  float v = elu_f(p + vb1[j]);
  if (half == 0) vs[wave][j] = v;
  __syncthreads();
  if (lane < 4 && node < n) {
    float o = vb2[lane];
#pragma unroll
    for (int jj = 0; jj < 32; ++jj) o += vs[wave][jj] * vw2[lane * 32 + jj];
    out[(size_t)node * 4 + lane] = o;
  }
}

extern "C" void kernel_launch(void* const* d_in, const int* in_sizes, int n_in,
                              void* d_out, int out_size, void* d_ws, size_t ws_size,
                              hipStream_t stream) {
  const float* x      = (const float*)d_in[0];
  const int*   esrc   = (const int*)d_in[1];
  const int*   edst   = (const int*)d_in[2];
  const float* proj_w = (const float*)d_in[3];
  const float* proj_b = (const float*)d_in[4];
  const float* w[3]   = {(const float*)d_in[5],  (const float*)d_in[11], (const float*)d_in[17]};
  const float* a_s[3] = {(const float*)d_in[6],  (const float*)d_in[12], (const float*)d_in[18]};
  const float* a_d[3] = {(const float*)d_in[7],  (const float*)d_in[13], (const float*)d_in[19]};
  const float* bb[3]  = {(const float*)d_in[8],  (const float*)d_in[14], (const float*)d_in[20]};
  const float* gg[3]  = {(const float*)d_in[9],  (const float*)d_in[15], (const float*)d_in[21]};
  const float* be[3]  = {(const float*)d_in[10], (const float*)d_in[16], (const float*)d_in[22]};
  const float* vw1 = (const float*)d_in[23];
  const float* vb1 = (const float*)d_in[24];
  const float* vw2 = (const float*)d_in[25];
  const float* vb2 = (const float*)d_in[26];
  float* outp = (float*)d_out;

  const int n = in_sizes[0] / 128;
  const int E = in_sizes[1];
  const int EE = E + n;

  // workspace layout
  float* bufA  = (float*)d_ws;                 // n*256
  float* bufB  = bufA + (size_t)n * 256;       // n*256
  float* asrcN = bufB + (size_t)n * 256;       // n*4
  float* adstN = asrcN + (size_t)n * 4;        // n*4
  int* deg    = (int*)(adstN + (size_t)n * 4); // n
  int* rowptr = deg + n;                       // n+1
  int* cursor = rowptr + n + 1;                // n
  int* col    = cursor + n;                    // EE

  // ---- CSR build (graph constant across layers) ----
  hipMemsetAsync(deg, 0, (size_t)n * sizeof(int), stream);
  deg_count_k<<<(EE + 255) / 256, 256, 0, stream>>>(esrc, edst, E, n, deg);
  scan_rowptr_k<<<1, 1024, 0, stream>>>(deg, rowptr, n);
  copy_int_k<<<(n + 255) / 256, 256, 0, stream>>>(rowptr, cursor, n);
  scatter_k<<<(EE + 255) / 256, 256, 0, stream>>>(esrc, edst, E, n, cursor, col);

  const int nb4 = (n + 3) / 4;
  dim3 blk(256);

  // ---- projection: bufA[n,64] = elu(x @ proj_w^T + proj_b) ----
  gemm_nt_k<1, 1><<<dim3((n + 63) / 64, 1), blk, 0, stream>>>(x, proj_w, proj_b, bufA, n, 128, 64);

  const int Kin[3] = {64, 256, 256};
  for (int i = 0; i < 3; ++i) {
    // feat = in @ w^T : bufB[n,256]
    gemm_nt_k<0, 0><<<dim3((n + 63) / 64, 4), blk, 0, stream>>>(bufA, w[i], nullptr, bufB, n, Kin[i], 256);
    attn_scores_k<<<nb4, blk, 0, stream>>>(bufB, a_s[i], a_d[i], asrcN, adstN, n);
    gat_aggregate_k<<<nb4, blk, 0, stream>>>(bufB, asrcN, adstN, rowptr, col, bufA, n);
    if (i < 2) {
      post_concat_k<<<nb4, blk, 0, stream>>>(bufA, bb[i], gg[i], be[i], n);
    } else {
      post_mean_k<<<nb4, blk, 0, stream>>>(bufA, bb[i], gg[i], be[i], bufB, n);
    }
  }

  // ---- value head ----
  value_head_k<<<nb4, blk, 0, stream>>>(bufB, vw1, vb1, vw2, vb2, outp, n);
}

// Round 2
// 656.929 us; speedup vs baseline: 1.6733x; 1.6733x over previous
//
#include <hip/hip_runtime.h>

typedef unsigned short u16;
typedef u16 u16x4 __attribute__((ext_vector_type(4)));
typedef short short8 __attribute__((ext_vector_type(8)));
typedef float f32x4 __attribute__((ext_vector_type(4)));

__device__ __forceinline__ float elu_f(float x) { return x > 0.f ? x : expm1f(x); }
__device__ __forceinline__ float lrelu_f(float x) { return x > 0.f ? x : 0.2f * x; }

__device__ __forceinline__ u16 f2b(float f) {
  union { float f; unsigned u; } v; v.f = f;
  unsigned r = v.u + 0x7FFF + ((v.u >> 16) & 1);
  return (u16)(r >> 16);
}
__device__ __forceinline__ float b2f(u16 u) {
  union { unsigned u; float f; } v; v.u = ((unsigned)u) << 16; return v.f;
}

// ---------------- CSR build ----------------
__global__ void deg_count_k(const int* __restrict__ src, const int* __restrict__ dst,
                            int E, int n, int* __restrict__ deg) {
  int e = blockIdx.x * blockDim.x + threadIdx.x;
  if (e < E) {
    atomicAdd(&deg[dst[e]], 1);
  } else if (e < E + n) {
    atomicAdd(&deg[e - E], 1);  // self loop
  }
}

// work-efficient single-block scan: 1024 threads, each scans ~n/1024 serially
__global__ void scan_rowptr_k(const int* __restrict__ deg, int* __restrict__ rowptr, int n) {
  __shared__ int ts[1024];
  int tid = threadIdx.x;
  int per = (n + 1023) / 1024;
  int s0 = tid * per;
  int s1 = s0 + per; if (s1 > n) s1 = n;
  int sum = 0;
  for (int i = s0; i < s1; ++i) sum += deg[i];
  ts[tid] = sum;
  __syncthreads();
  for (int off = 1; off < 1024; off <<= 1) {
    int v = (tid >= off) ? ts[tid - off] : 0;
    __syncthreads();
    ts[tid] += v;
    __syncthreads();
  }
  int excl = (tid == 0) ? 0 : ts[tid - 1];
  if (tid == 0) rowptr[0] = 0;
  for (int i = s0; i < s1; ++i) { excl += deg[i]; rowptr[i + 1] = excl; }
}

__global__ void copy_int_k(const int* __restrict__ a, int* __restrict__ b, int n) {
  int i = blockIdx.x * blockDim.x + threadIdx.x;
  if (i < n) b[i] = a[i];
}

__global__ void scatter_k(const int* __restrict__ src, const int* __restrict__ dst,
                          int E, int n, int* __restrict__ cursor, int* __restrict__ col) {
  int e = blockIdx.x * blockDim.x + threadIdx.x;
  if (e < E) {
    int d = dst[e];
    int pos = atomicAdd(&cursor[d], 1);
    col[pos] = src[e];
  } else if (e < E + n) {
    int d = e - E;
    int pos = atomicAdd(&cursor[d], 1);
    col[pos] = d;  // self loop
  }
}

__global__ void cvt_w_k(const float* __restrict__ w, u16* __restrict__ o, int sz) {
  int i = blockIdx.x * blockDim.x + threadIdx.x;
  if (i < sz) o[i] = f2b(w[i]);
}

// ---------------- f32 GEMM (proj only): C = A[n,K] @ W[ncols,K]^T, bias+ELU, bf16 out ----------------
template <int BIAS, int ELU, int OUTBF>
__global__ __launch_bounds__(256) void gemm_nt_k(const float* __restrict__ A,
                                                 const float* __restrict__ W,
                                                 const float* __restrict__ bias,
                                                 void* __restrict__ C,
                                                 int n, int K, int ncols, int ldc) {
  __shared__ float As[64][33];
  __shared__ float Ws[64][33];
  const int t = threadIdx.x;
  const int tx = t & 15, ty = t >> 4;
  const int row0 = blockIdx.x * 64, col0 = blockIdx.y * 64;
  float acc[4][4] = {};
  for (int k0 = 0; k0 < K; k0 += 32) {
#pragma unroll
    for (int i = 0; i < 2; ++i) {
      int idx = t + i * 256;
      int r = idx >> 3;
      int c = (idx & 7) << 2;
      int gr = row0 + r;
      float4 av = make_float4(0.f, 0.f, 0.f, 0.f);
      if (gr < n) av = *reinterpret_cast<const float4*>(&A[(size_t)gr * K + k0 + c]);
      As[r][c] = av.x; As[r][c + 1] = av.y; As[r][c + 2] = av.z; As[r][c + 3] = av.w;
      float4 wv = *reinterpret_cast<const float4*>(&W[(size_t)(col0 + r) * K + k0 + c]);
      Ws[r][c] = wv.x; Ws[r][c + 1] = wv.y; Ws[r][c + 2] = wv.z; Ws[r][c + 3] = wv.w;
    }
    __syncthreads();
#pragma unroll
    for (int kk = 0; kk < 32; ++kk) {
      float a0 = As[ty * 4 + 0][kk], a1 = As[ty * 4 + 1][kk];
      float a2 = As[ty * 4 + 2][kk], a3 = As[ty * 4 + 3][kk];
      float b0 = Ws[tx * 4 + 0][kk], b1 = Ws[tx * 4 + 1][kk];
      float b2 = Ws[tx * 4 + 2][kk], b3 = Ws[tx * 4 + 3][kk];
      acc[0][0] += a0 * b0; acc[0][1] += a0 * b1; acc[0][2] += a0 * b2; acc[0][3] += a0 * b3;
      acc[1][0] += a1 * b0; acc[1][1] += a1 * b1; acc[1][2] += a1 * b2; acc[1][3] += a1 * b3;
      acc[2][0] += a2 * b0; acc[2][1] += a2 * b1; acc[2][2] += a2 * b2; acc[2][3] += a2 * b3;
      acc[3][0] += a3 * b0; acc[3][1] += a3 * b1; acc[3][2] += a3 * b2; acc[3][3] += a3 * b3;
    }
    __syncthreads();
  }
#pragma unroll
  for (int i = 0; i < 4; ++i) {
    int r = row0 + ty * 4 + i;
    if (r >= n) continue;
    int cc = col0 + tx * 4;
    float o[4];
#pragma unroll
    for (int j = 0; j < 4; ++j) {
      float v = acc[i][j];
      if (BIAS) v += bias[cc + j];
      if (ELU) v = elu_f(v);
      o[j] = v;
    }
    if (OUTBF) {
      u16x4 v4;
      v4.x = f2b(o[0]); v4.y = f2b(o[1]); v4.z = f2b(o[2]); v4.w = f2b(o[3]);
      *reinterpret_cast<u16x4*>(&((u16*)C)[(size_t)r * ldc + cc]) = v4;
    } else {
      float4 v4 = make_float4(o[0], o[1], o[2], o[3]);
      *reinterpret_cast<float4*>(&((float*)C)[(size_t)r * ldc + cc]) = v4;
    }
  }
}

// ---------------- bf16 MFMA GEMM: Cb[n,256](bf16) = A[n,K](bf16,lda) @ W[256,K](bf16)^T ----------------
__global__ __launch_bounds__(256) void gemm_bf16_k(const u16* __restrict__ A, int lda,
                                                   const u16* __restrict__ W,
                                                   u16* __restrict__ Cb,
                                                   int n, int K) {
  __shared__ int4 Abuf[1024];  // 128 rows x 128B, XOR-swizzled
  __shared__ int4 Bbuf[1024];
  char* Asb = (char*)Abuf;
  char* Bsb = (char*)Bbuf;
  const int t = threadIdx.x;
  const int lane = t & 63, w = t >> 6;
  const int wrow = w >> 1, wcol = w & 1;
  const int row0 = blockIdx.x * 128, col0 = blockIdx.y * 128;
  f32x4 acc[4][4];
#pragma unroll
  for (int m = 0; m < 4; ++m)
#pragma unroll
    for (int nf = 0; nf < 4; ++nf) acc[m][nf] = (f32x4){0.f, 0.f, 0.f, 0.f};

  for (int k0 = 0; k0 < K; k0 += 64) {
    // stage 128x64 bf16 tiles of A and W, swizzle: byte-in-row ^= (row&7)<<4
#pragma unroll
    for (int i = 0; i < 4; ++i) {
      int ci = i * 256 + t;           // 16B chunk index, 0..1023
      int r = ci >> 3;                // row 0..127
      int b = (ci & 7) << 4;          // byte-in-row
      int sw = b ^ ((r & 7) << 4);
      int ar = row0 + r; ar = ar < n ? ar : n - 1;
      int4 av = *reinterpret_cast<const int4*>(&A[(size_t)ar * lda + k0 + (b >> 1)]);
      *reinterpret_cast<int4*>(Asb + r * 128 + sw) = av;
      int4 wv = *reinterpret_cast<const int4*>(&W[(size_t)(col0 + r) * K + k0 + (b >> 1)]);
      *reinterpret_cast<int4*>(Bsb + r * 128 + sw) = wv;
    }
    __syncthreads();
#pragma unroll
    for (int ks = 0; ks < 2; ++ks) {
      short8 af[4], bf[4];
      int kb = ks * 64 + ((lane >> 4) << 4);
#pragma unroll
      for (int m = 0; m < 4; ++m) {
        int r = wrow * 64 + m * 16 + (lane & 15);
        af[m] = *reinterpret_cast<const short8*>(Asb + r * 128 + (kb ^ ((r & 7) << 4)));
      }
#pragma unroll
      for (int nf = 0; nf < 4; ++nf) {
        int r = wcol * 64 + nf * 16 + (lane & 15);
        bf[nf] = *reinterpret_cast<const short8*>(Bsb + r * 128 + (kb ^ ((r & 7) << 4)));
      }
#pragma unroll
      for (int m = 0; m < 4; ++m)
#pragma unroll
        for (int nf = 0; nf < 4; ++nf)
          acc[m][nf] = __builtin_amdgcn_mfma_f32_16x16x32_bf16(af[m], bf[nf], acc[m][nf], 0, 0, 0);
    }
    __syncthreads();
  }
  // epilogue: C/D layout col=lane&15, row=(lane>>4)*4+j
#pragma unroll
  for (int m = 0; m < 4; ++m) {
#pragma unroll
    for (int j = 0; j < 4; ++j) {
      int rg = row0 + wrow * 64 + m * 16 + (lane >> 4) * 4 + j;
      if (rg >= n) continue;
#pragma unroll
      for (int nf = 0; nf < 4; ++nf) {
        int cg = col0 + wcol * 64 + nf * 16 + (lane & 15);
        Cb[(size_t)rg * 256 + cg] = f2b(acc[m][nf][j]);
      }
    }
  }
}

// ---------------- attention scores from bf16 feat ----------------
__global__ void attn_scores_k(const u16* __restrict__ feat, const float* __restrict__ a_s,
                              const float* __restrict__ a_d, float* __restrict__ asrcN,
                              float* __restrict__ adstN, int n) {
  int wave = threadIdx.x >> 6, lane = threadIdx.x & 63;
  int node = blockIdx.x * 4 + wave;
  if (node >= n) return;
  u16x4 f = *reinterpret_cast<const u16x4*>(&feat[(size_t)node * 256 + lane * 4]);
  float4 as = *reinterpret_cast<const float4*>(&a_s[lane * 4]);
  float4 ad = *reinterpret_cast<const float4*>(&a_d[lane * 4]);
  float fx = b2f(f.x), fy = b2f(f.y), fz = b2f(f.z), fw = b2f(f.w);
  float ps = fx * as.x + fy * as.y + fz * as.z + fw * as.w;
  float pd = fx * ad.x + fy * ad.y + fz * ad.z + fw * ad.w;
#pragma unroll
  for (int off = 1; off < 16; off <<= 1) {
    ps += __shfl_xor(ps, off);
    pd += __shfl_xor(pd, off);
  }
  if ((lane & 15) == 0) {
    int h = lane >> 4;
    asrcN[(size_t)node * 4 + h] = ps;
    adstN[(size_t)node * 4 + h] = pd;
  }
}

// ---------------- GAT aggregation (wave per node, bf16 gather, no-max softmax) ----------------
__global__ void gat_aggregate_k(const u16* __restrict__ feat, const float* __restrict__ asrcN,
                                const float* __restrict__ adstN, const int* __restrict__ rowptr,
                                const int* __restrict__ col, float* __restrict__ out, int n) {
  int wave = threadIdx.x >> 6, lane = threadIdx.x & 63;
  int node = blockIdx.x * 4 + wave;
  if (node >= n) return;
  int h = lane >> 4;
  float adst_h = adstN[(size_t)node * 4 + h];
  int s0 = rowptr[node], s1 = rowptr[node + 1];
  float ax = 0.f, ay = 0.f, az = 0.f, aw = 0.f, den = 0.f;
  for (int e = s0; e < s1; ++e) {
    int s = col[e];
    float a = lrelu_f(asrcN[(size_t)s * 4 + h] + adst_h);
    float ex = __expf(a);  // softmax is shift-invariant; |a| <~ 5 so no overflow
    den += ex;
    u16x4 f = *reinterpret_cast<const u16x4*>(&feat[(size_t)s * 256 + lane * 4]);
    ax += ex * b2f(f.x); ay += ex * b2f(f.y); az += ex * b2f(f.z); aw += ex * b2f(f.w);
  }
  float inv = 1.f / den;  // self-loop guarantees den > 0
  float4 o = make_float4(ax * inv, ay * inv, az * inv, aw * inv);
  *reinterpret_cast<float4*>(&out[(size_t)node * 256 + lane * 4]) = o;
}

// ---------------- bias + LayerNorm(256) + ELU; read f32 row, write bf16 into same row (in-place) ----------------
__global__ void post_concat_k(float* __restrict__ io, const float* __restrict__ bias,
                              const float* __restrict__ g, const float* __restrict__ be, int n) {
  int wave = threadIdx.x >> 6, lane = threadIdx.x & 63;
  int node = blockIdx.x * 4 + wave;
  if (node >= n) return;
  float4 v = *reinterpret_cast<const float4*>(&io[(size_t)node * 256 + lane * 4]);
  float4 b = *reinterpret_cast<const float4*>(&bias[lane * 4]);
  v.x += b.x; v.y += b.y; v.z += b.z; v.w += b.w;
  float s = v.x + v.y + v.z + v.w;
#pragma unroll
  for (int off = 1; off < 64; off <<= 1) s += __shfl_xor(s, off);
  float mu = s * (1.f / 256.f);
  float dx = v.x - mu, dy = v.y - mu, dz = v.z - mu, dw = v.w - mu;
  float q = dx * dx + dy * dy + dz * dz + dw * dw;
#pragma unroll
  for (int off = 1; off < 64; off <<= 1) q += __shfl_xor(q, off);
  float inv = rsqrtf(q * (1.f / 256.f) + 1e-5f);
  float4 gg = *reinterpret_cast<const float4*>(&g[lane * 4]);
  float4 bb = *reinterpret_cast<const float4*>(&be[lane * 4]);
  u16x4 o;
  o.x = f2b(elu_f(dx * inv * gg.x + bb.x));
  o.y = f2b(elu_f(dy * inv * gg.y + bb.y));
  o.z = f2b(elu_f(dz * inv * gg.z + bb.z));
  o.w = f2b(elu_f(dw * inv * gg.w + bb.w));
  // write bf16 into first half of the same 1KB row slot (all reads of this row done by this wave)
  u16* rowb = (u16*)io + (size_t)node * 512;
  *reinterpret_cast<u16x4*>(&rowb[lane * 4]) = o;
}

// ---------------- head-mean + bias + LayerNorm(64) + ELU (f32 in, f32 out) ----------------
__global__ void post_mean_k(const float* __restrict__ in, const float* __restrict__ bias,
                            const float* __restrict__ g, const float* __restrict__ be,
                            float* __restrict__ out, int n) {
  int wave = threadIdx.x >> 6, lane = threadIdx.x & 63;
  int node = blockIdx.x * 4 + wave;
  if (node >= n) return;
  const float* r = &in[(size_t)node * 256];
  float v = 0.25f * (r[lane] + r[64 + lane] + r[128 + lane] + r[192 + lane]) + bias[lane];
  float s = v;
#pragma unroll
  for (int off = 1; off < 64; off <<= 1) s += __shfl_xor(s, off);
  float mu = s * (1.f / 64.f);
  float d = v - mu;
  float q = d * d;
#pragma unroll
  for (int off = 1; off < 64; off <<= 1) q += __shfl_xor(q, off);
  float inv = rsqrtf(q * (1.f / 64.f) + 1e-5f);
  out[(size_t)node * 64 + lane] = elu_f(d * inv * g[lane] + be[lane]);
}

// ---------------- value head: out[n,4] ----------------
__global__ void value_head_k(const float* __restrict__ hh, const float* __restrict__ vw1,
                             const float* __restrict__ vb1, const float* __restrict__ vw2,
                             const float* __restrict__ vb2, float* __restrict__ out, int n) {
  __shared__ float w1s[32 * 65];
  __shared__ float hs[4][64];
  __shared__ float vs[4][33];
  int tid = threadIdx.x;
  for (int i = tid; i < 2048; i += 256) w1s[(i >> 6) * 65 + (i & 63)] = vw1[i];
  int wave = tid >> 6, lane = tid & 63;
  int node = blockIdx.x * 4 + wave;
  int nc = node < n ? node : n - 1;
  hs[wave][lane] = hh[(size_t)nc * 64 + lane];
  __syncthreads();
  int j = lane & 31, half = lane >> 5;
  float p = 0.f;
#pragma unroll
  for (int c = 0; c < 32; ++c) p += hs[wave][half * 32 + c] * w1s[j * 65 + half * 32 + c];
  p += __shfl_xor(p, 32);
  float v = elu_f(p + vb1[j]);
  if (half == 0) vs[wave][j] = v;
  __syncthreads();
  if (lane < 4 && node < n) {
    float o = vb2[lane];
#pragma unroll
    for (int jj = 0; jj < 32; ++jj) o += vs[wave][jj] * vw2[lane * 32 + jj];
    out[(size_t)node * 4 + lane] = o;
  }
}

extern "C" void kernel_launch(void* const* d_in, const int* in_sizes, int n_in,
                              void* d_out, int out_size, void* d_ws, size_t ws_size,
                              hipStream_t stream) {
  const float* x      = (const float*)d_in[0];
  const int*   esrc   = (const int*)d_in[1];
  const int*   edst   = (const int*)d_in[2];
  const float* proj_w = (const float*)d_in[3];
  const float* proj_b = (const float*)d_in[4];
  const float* w[3]   = {(const float*)d_in[5],  (const float*)d_in[11], (const float*)d_in[17]};
  const float* a_s[3] = {(const float*)d_in[6],  (const float*)d_in[12], (const float*)d_in[18]};
  const float* a_d[3] = {(const float*)d_in[7],  (const float*)d_in[13], (const float*)d_in[19]};
  const float* bb[3]  = {(const float*)d_in[8],  (const float*)d_in[14], (const float*)d_in[20]};
  const float* gg[3]  = {(const float*)d_in[9],  (const float*)d_in[15], (const float*)d_in[21]};
  const float* be[3]  = {(const float*)d_in[10], (const float*)d_in[16], (const float*)d_in[22]};
  const float* vw1 = (const float*)d_in[23];
  const float* vb1 = (const float*)d_in[24];
  const float* vw2 = (const float*)d_in[25];
  const float* vb2 = (const float*)d_in[26];
  float* outp = (float*)d_out;

  const int n = in_sizes[0] / 128;
  const int E = in_sizes[1];
  const int EE = E + n;

  // ---- workspace layout (256B-aligned chunks) ----
  char* p = (char*)d_ws;
  auto alloc = [&](size_t bytes) { char* r = p; p += (bytes + 255) & ~(size_t)255; return r; };
  float* BIG   = (float*)alloc((size_t)n * 1024);  // [n] rows of 1KB: f32 [n,256] view AND bf16-A [n,*512] view
  u16*   featB = (u16*)alloc((size_t)n * 512);     // bf16 [n,256]; later reused as f32 hfinal [n,64]
  float* asrcN = (float*)alloc((size_t)n * 16);
  float* adstN = (float*)alloc((size_t)n * 16);
  u16* wb[3];
  wb[0] = (u16*)alloc(256 * 64 * 2);
  wb[1] = (u16*)alloc(256 * 256 * 2);
  wb[2] = (u16*)alloc(256 * 256 * 2);
  int* deg    = (int*)alloc((size_t)n * 4);
  int* rowptr = (int*)alloc((size_t)(n + 1) * 4);
  int* cursor = (int*)alloc((size_t)n * 4);
  int* col    = (int*)alloc((size_t)EE * 4);
  float* hfinal = (float*)featB;

  // ---- CSR build (graph constant across layers) ----
  hipMemsetAsync(deg, 0, (size_t)n * sizeof(int), stream);
  deg_count_k<<<(EE + 255) / 256, 256, 0, stream>>>(esrc, edst, E, n, deg);
  scan_rowptr_k<<<1, 1024, 0, stream>>>(deg, rowptr, n);
  copy_int_k<<<(n + 255) / 256, 256, 0, stream>>>(rowptr, cursor, n);
  scatter_k<<<(EE + 255) / 256, 256, 0, stream>>>(esrc, edst, E, n, cursor, col);

  // ---- weight conversions to bf16 ----
  cvt_w_k<<<(256 * 64 + 255) / 256, 256, 0, stream>>>(w[0], wb[0], 256 * 64);
  cvt_w_k<<<(256 * 256 + 255) / 256, 256, 0, stream>>>(w[1], wb[1], 256 * 256);
  cvt_w_k<<<(256 * 256 + 255) / 256, 256, 0, stream>>>(w[2], wb[2], 256 * 256);

  const int nb4 = (n + 3) / 4;
  dim3 blk(256);

  // ---- projection: BIG(bf16 rows, lda=512) = elu(x @ proj_w^T + proj_b) ----
  gemm_nt_k<1, 1, 1><<<dim3((n + 63) / 64, 1), blk, 0, stream>>>(x, proj_w, proj_b, (void*)BIG, n, 128, 64, 512);

  const int Kin[3] = {64, 256, 256};
  for (int i = 0; i < 3; ++i) {
    gemm_bf16_k<<<dim3((n + 127) / 128, 2), blk, 0, stream>>>((const u16*)BIG, 512, wb[i], featB, n, Kin[i]);
    attn_scores_k<<<nb4, blk, 0, stream>>>(featB, a_s[i], a_d[i], asrcN, adstN, n);
    gat_aggregate_k<<<nb4, blk, 0, stream>>>(featB, asrcN, adstN, rowptr, col, BIG, n);
    if (i < 2) {
      post_concat_k<<<nb4, blk, 0, stream>>>(BIG, bb[i], gg[i], be[i], n);
    } else {
      post_mean_k<<<nb4, blk, 0, stream>>>(BIG, bb[i], gg[i], be[i], hfinal, n);
    }
  }

  // ---- value head ----
  value_head_k<<<nb4, blk, 0, stream>>>(hfinal, vw1, vb1, vw2, vb2, outp, n);
}

// Round 3
// 547.595 us; speedup vs baseline: 2.0074x; 1.1997x over previous
//
#include <hip/hip_runtime.h>

typedef unsigned short u16;
typedef u16 u16x4 __attribute__((ext_vector_type(4)));
typedef short short8 __attribute__((ext_vector_type(8)));
typedef float f32x4 __attribute__((ext_vector_type(4)));

__device__ __forceinline__ float elu_f(float x) { return x > 0.f ? x : expm1f(x); }
__device__ __forceinline__ float lrelu_f(float x) { return x > 0.f ? x : 0.2f * x; }

__device__ __forceinline__ u16 f2b(float f) {
  union { float f; unsigned u; } v; v.f = f;
  unsigned r = v.u + 0x7FFF + ((v.u >> 16) & 1);
  return (u16)(r >> 16);
}
__device__ __forceinline__ float b2f(u16 u) {
  union { unsigned u; float f; } v; v.u = ((unsigned)u) << 16; return v.f;
}

// ---------------- CSR build ----------------
__global__ void deg_count_k(const int* __restrict__ src, const int* __restrict__ dst,
                            int E, int n, int* __restrict__ deg) {
  int e = blockIdx.x * blockDim.x + threadIdx.x;
  if (e < E) {
    atomicAdd(&deg[dst[e]], 1);
  } else if (e < E + n) {
    atomicAdd(&deg[e - E], 1);  // self loop
  }
}

// work-efficient single-block scan; also emits cursor (= rowptr[i]) for scatter
__global__ void scan_rowptr_k(const int* __restrict__ deg, int* __restrict__ rowptr,
                              int* __restrict__ cursor, int n) {
  __shared__ int ts[1024];
  int tid = threadIdx.x;
  int per = (n + 1023) / 1024;
  int s0 = tid * per;
  int s1 = s0 + per; if (s1 > n) s1 = n;
  int sum = 0;
  for (int i = s0; i < s1; ++i) sum += deg[i];
  ts[tid] = sum;
  __syncthreads();
  for (int off = 1; off < 1024; off <<= 1) {
    int v = (tid >= off) ? ts[tid - off] : 0;
    __syncthreads();
    ts[tid] += v;
    __syncthreads();
  }
  int excl = (tid == 0) ? 0 : ts[tid - 1];
  if (tid == 0) rowptr[0] = 0;
  for (int i = s0; i < s1; ++i) {
    cursor[i] = excl;
    excl += deg[i];
    rowptr[i + 1] = excl;
  }
}

__global__ void scatter_k(const int* __restrict__ src, const int* __restrict__ dst,
                          int E, int n, int* __restrict__ cursor, int* __restrict__ col) {
  int e = blockIdx.x * blockDim.x + threadIdx.x;
  if (e < E) {
    int d = dst[e];
    int pos = atomicAdd(&cursor[d], 1);
    col[pos] = src[e];
  } else if (e < E + n) {
    int d = e - E;
    int pos = atomicAdd(&cursor[d], 1);
    col[pos] = d;  // self loop
  }
}

__global__ void cvt_w_k(const float* __restrict__ w, u16* __restrict__ o, int sz) {
  int i = blockIdx.x * blockDim.x + threadIdx.x;
  if (i < sz) o[i] = f2b(w[i]);
}

// vectorized f32 -> bf16, sz multiple of 8
__global__ void cvt8_k(const float* __restrict__ in, u16* __restrict__ o, int sz) {
  int i = (blockIdx.x * blockDim.x + threadIdx.x) * 8;
  if (i >= sz) return;
  float4 a = *reinterpret_cast<const float4*>(&in[i]);
  float4 b = *reinterpret_cast<const float4*>(&in[i + 4]);
  u16x4 o0, o1;
  o0.x = f2b(a.x); o0.y = f2b(a.y); o0.z = f2b(a.z); o0.w = f2b(a.w);
  o1.x = f2b(b.x); o1.y = f2b(b.y); o1.z = f2b(b.z); o1.w = f2b(b.w);
  *reinterpret_cast<u16x4*>(&o[i]) = o0;
  *reinterpret_cast<u16x4*>(&o[i + 4]) = o1;
}

// ---------------- bf16 MFMA GEMM: Cb[n,ncols](bf16,ldc) = A[n,K](bf16,lda) @ W[ncols,K]^T ----------------
template <int BIASELU>
__global__ __launch_bounds__(256) void gemm_bf16_k(const u16* __restrict__ A, int lda,
                                                   const u16* __restrict__ W,
                                                   const float* __restrict__ bias,
                                                   u16* __restrict__ Cb, int ldc,
                                                   int n, int K, int ncols) {
  __shared__ int4 Abuf[1024];  // 128 rows x 128B, XOR-swizzled
  __shared__ int4 Bbuf[1024];
  char* Asb = (char*)Abuf;
  char* Bsb = (char*)Bbuf;
  const int t = threadIdx.x;
  const int lane = t & 63, w = t >> 6;
  const int wrow = w >> 1, wcol = w & 1;
  const int row0 = blockIdx.x * 128, col0 = blockIdx.y * 128;
  f32x4 acc[4][4];
#pragma unroll
  for (int m = 0; m < 4; ++m)
#pragma unroll
    for (int nf = 0; nf < 4; ++nf) acc[m][nf] = (f32x4){0.f, 0.f, 0.f, 0.f};

  for (int k0 = 0; k0 < K; k0 += 64) {
#pragma unroll
    for (int i = 0; i < 4; ++i) {
      int ci = i * 256 + t;           // 16B chunk index, 0..1023
      int r = ci >> 3;                // row 0..127
      int b = (ci & 7) << 4;          // byte-in-row
      int sw = b ^ ((r & 7) << 4);
      int ar = row0 + r; ar = ar < n ? ar : n - 1;
      int4 av = *reinterpret_cast<const int4*>(&A[(size_t)ar * lda + k0 + (b >> 1)]);
      *reinterpret_cast<int4*>(Asb + r * 128 + sw) = av;
      int wr = col0 + r; wr = wr < ncols ? wr : ncols - 1;
      int4 wv = *reinterpret_cast<const int4*>(&W[(size_t)wr * K + k0 + (b >> 1)]);
      *reinterpret_cast<int4*>(Bsb + r * 128 + sw) = wv;
    }
    __syncthreads();
#pragma unroll
    for (int ks = 0; ks < 2; ++ks) {
      short8 af[4], bf[4];
      int kb = ks * 64 + ((lane >> 4) << 4);
#pragma unroll
      for (int m = 0; m < 4; ++m) {
        int r = wrow * 64 + m * 16 + (lane & 15);
        af[m] = *reinterpret_cast<const short8*>(Asb + r * 128 + (kb ^ ((r & 7) << 4)));
      }
#pragma unroll
      for (int nf = 0; nf < 4; ++nf) {
        int r = wcol * 64 + nf * 16 + (lane & 15);
        bf[nf] = *reinterpret_cast<const short8*>(Bsb + r * 128 + (kb ^ ((r & 7) << 4)));
      }
#pragma unroll
      for (int m = 0; m < 4; ++m)
#pragma unroll
        for (int nf = 0; nf < 4; ++nf)
          acc[m][nf] = __builtin_amdgcn_mfma_f32_16x16x32_bf16(af[m], bf[nf], acc[m][nf], 0, 0, 0);
    }
    __syncthreads();
  }
  // epilogue: C/D layout col=lane&15, row=(lane>>4)*4+j
#pragma unroll
  for (int m = 0; m < 4; ++m) {
#pragma unroll
    for (int j = 0; j < 4; ++j) {
      int rg = row0 + wrow * 64 + m * 16 + (lane >> 4) * 4 + j;
      if (rg >= n) continue;
#pragma unroll
      for (int nf = 0; nf < 4; ++nf) {
        int cg = col0 + wcol * 64 + nf * 16 + (lane & 15);
        if (cg >= ncols) continue;
        float v = acc[m][nf][j];
        if (BIASELU) v = elu_f(v + bias[cg]);
        Cb[(size_t)rg * ldc + cg] = f2b(v);
      }
    }
  }
}

// ---------------- attention scores from bf16 feat ----------------
__global__ void attn_scores_k(const u16* __restrict__ feat, const float* __restrict__ a_s,
                              const float* __restrict__ a_d, float* __restrict__ asrcN,
                              float* __restrict__ adstN, int n) {
  int wave = threadIdx.x >> 6, lane = threadIdx.x & 63;
  int node = blockIdx.x * 4 + wave;
  if (node >= n) return;
  u16x4 f = *reinterpret_cast<const u16x4*>(&feat[(size_t)node * 256 + lane * 4]);
  float4 as = *reinterpret_cast<const float4*>(&a_s[lane * 4]);
  float4 ad = *reinterpret_cast<const float4*>(&a_d[lane * 4]);
  float fx = b2f(f.x), fy = b2f(f.y), fz = b2f(f.z), fw = b2f(f.w);
  float ps = fx * as.x + fy * as.y + fz * as.z + fw * as.w;
  float pd = fx * ad.x + fy * ad.y + fz * ad.z + fw * ad.w;
#pragma unroll
  for (int off = 1; off < 16; off <<= 1) {
    ps += __shfl_xor(ps, off);
    pd += __shfl_xor(pd, off);
  }
  if ((lane & 15) == 0) {
    int h = lane >> 4;
    asrcN[(size_t)node * 4 + h] = ps;
    adstN[(size_t)node * 4 + h] = pd;
  }
}

// ---------------- fused GAT aggregation + bias + LayerNorm + ELU ----------------
// MODE 0: LN(256) -> bf16 row written at (u16*)out + node*512 (lda-512 A layout)
// MODE 1: head-mean -> bias -> LN(64) -> ELU -> f32 out[node*64..]
template <int MODE>
__global__ void gat_agg_fused_k(const u16* __restrict__ feat, const float* __restrict__ asrcN,
                                const float* __restrict__ adstN, const int* __restrict__ rowptr,
                                const int* __restrict__ col,
                                const float* __restrict__ bias, const float* __restrict__ g,
                                const float* __restrict__ be, void* __restrict__ out, int n) {
  int wave = threadIdx.x >> 6, lane = threadIdx.x & 63;
  int node = blockIdx.x * 4 + wave;
  if (node >= n) return;
  int h = lane >> 4;
  float adst_h = adstN[(size_t)node * 4 + h];
  int s0 = rowptr[node], s1 = rowptr[node + 1];
  float ax = 0.f, ay = 0.f, az = 0.f, aw = 0.f, den = 0.f;
  int e = s0;
  // unroll-4: 4 col loads then 8 gathers in flight per wave (MLP)
  for (; e + 4 <= s1; e += 4) {
    int sa = col[e + 0], sb = col[e + 1], sc = col[e + 2], sd = col[e + 3];
    float ea = asrcN[(size_t)sa * 4 + h];
    float eb = asrcN[(size_t)sb * 4 + h];
    float ec = asrcN[(size_t)sc * 4 + h];
    float ed = asrcN[(size_t)sd * 4 + h];
    u16x4 fa = *reinterpret_cast<const u16x4*>(&feat[(size_t)sa * 256 + lane * 4]);
    u16x4 fb = *reinterpret_cast<const u16x4*>(&feat[(size_t)sb * 256 + lane * 4]);
    u16x4 fc = *reinterpret_cast<const u16x4*>(&feat[(size_t)sc * 256 + lane * 4]);
    u16x4 fd = *reinterpret_cast<const u16x4*>(&feat[(size_t)sd * 256 + lane * 4]);
    float xa = __expf(lrelu_f(ea + adst_h));
    float xb = __expf(lrelu_f(eb + adst_h));
    float xc = __expf(lrelu_f(ec + adst_h));
    float xd = __expf(lrelu_f(ed + adst_h));
    den += (xa + xb) + (xc + xd);
    ax += xa * b2f(fa.x) + xb * b2f(fb.x) + xc * b2f(fc.x) + xd * b2f(fd.x);
    ay += xa * b2f(fa.y) + xb * b2f(fb.y) + xc * b2f(fc.y) + xd * b2f(fd.y);
    az += xa * b2f(fa.z) + xb * b2f(fb.z) + xc * b2f(fc.z) + xd * b2f(fd.z);
    aw += xa * b2f(fa.w) + xb * b2f(fb.w) + xc * b2f(fc.w) + xd * b2f(fd.w);
  }
  for (; e < s1; ++e) {
    int s = col[e];
    float a = lrelu_f(asrcN[(size_t)s * 4 + h] + adst_h);
    float ex = __expf(a);
    den += ex;
    u16x4 f = *reinterpret_cast<const u16x4*>(&feat[(size_t)s * 256 + lane * 4]);
    ax += ex * b2f(f.x); ay += ex * b2f(f.y); az += ex * b2f(f.z); aw += ex * b2f(f.w);
  }
  float inv = 1.f / den;  // self-loop guarantees den > 0; softmax shift-invariant, |a|<~5
  ax *= inv; ay *= inv; az *= inv; aw *= inv;

  if (MODE == 0) {
    float4 b4 = *reinterpret_cast<const float4*>(&bias[lane * 4]);
    float vx = ax + b4.x, vy = ay + b4.y, vz = az + b4.z, vw = aw + b4.w;
    float s = vx + vy + vz + vw;
#pragma unroll
    for (int off = 1; off < 64; off <<= 1) s += __shfl_xor(s, off);
    float mu = s * (1.f / 256.f);
    float dx = vx - mu, dy = vy - mu, dz = vz - mu, dw = vw - mu;
    float q = dx * dx + dy * dy + dz * dz + dw * dw;
#pragma unroll
    for (int off = 1; off < 64; off <<= 1) q += __shfl_xor(q, off);
    float inv2 = rsqrtf(q * (1.f / 256.f) + 1e-5f);
    float4 gg = *reinterpret_cast<const float4*>(&g[lane * 4]);
    float4 bb = *reinterpret_cast<const float4*>(&be[lane * 4]);
    u16x4 o;
    o.x = f2b(elu_f(dx * inv2 * gg.x + bb.x));
    o.y = f2b(elu_f(dy * inv2 * gg.y + bb.y));
    o.z = f2b(elu_f(dz * inv2 * gg.z + bb.z));
    o.w = f2b(elu_f(dw * inv2 * gg.w + bb.w));
    u16* rowb = (u16*)out + (size_t)node * 512;
    *reinterpret_cast<u16x4*>(&rowb[lane * 4]) = o;
  } else {
    // head-mean: sum over h (lane bits 4,5)
    ax += __shfl_xor(ax, 16); ax += __shfl_xor(ax, 32);
    ay += __shfl_xor(ay, 16); ay += __shfl_xor(ay, 32);
    az += __shfl_xor(az, 16); az += __shfl_xor(az, 32);
    aw += __shfl_xor(aw, 16); aw += __shfl_xor(aw, 32);
    int qd = lane & 15;
    float4 b4 = *reinterpret_cast<const float4*>(&bias[qd * 4]);
    float vx = 0.25f * ax + b4.x, vy = 0.25f * ay + b4.y;
    float vz = 0.25f * az + b4.z, vw = 0.25f * aw + b4.w;
    // LN over 64 cols; each col replicated 4x across lanes -> divide by 256
    float s = vx + vy + vz + vw;
#pragma unroll
    for (int off = 1; off < 64; off <<= 1) s += __shfl_xor(s, off);
    float mu = s * (1.f / 256.f);
    float dx = vx - mu, dy = vy - mu, dz = vz - mu, dw = vw - mu;
    float q = dx * dx + dy * dy + dz * dz + dw * dw;
#pragma unroll
    for (int off = 1; off < 64; off <<= 1) q += __shfl_xor(q, off);
    float inv2 = rsqrtf(q * (1.f / 256.f) + 1e-5f);
    if (lane < 16) {
      float4 gg = *reinterpret_cast<const float4*>(&g[qd * 4]);
      float4 bb = *reinterpret_cast<const float4*>(&be[qd * 4]);
      float4 o;
      o.x = elu_f(dx * inv2 * gg.x + bb.x);
      o.y = elu_f(dy * inv2 * gg.y + bb.y);
      o.z = elu_f(dz * inv2 * gg.z + bb.z);
      o.w = elu_f(dw * inv2 * gg.w + bb.w);
      *reinterpret_cast<float4*>(&((float*)out)[(size_t)node * 64 + qd * 4]) = o;
    }
  }
}

// ---------------- value head: out[n,4] ----------------
__global__ void value_head_k(const float* __restrict__ hh, const float* __restrict__ vw1,
                             const float* __restrict__ vb1, const float* __restrict__ vw2,
                             const float* __restrict__ vb2, float* __restrict__ out, int n) {
  __shared__ float w1s[32 * 65];
  __shared__ float hs[4][64];
  __shared__ float vs[4][33];
  int tid = threadIdx.x;
  for (int i = tid; i < 2048; i += 256) w1s[(i >> 6) * 65 + (i & 63)] = vw1[i];
  int wave = tid >> 6, lane = tid & 63;
  int node = blockIdx.x * 4 + wave;
  int nc = node < n ? node : n - 1;
  hs[wave][lane] = hh[(size_t)nc * 64 + lane];
  __syncthreads();
  int j = lane & 31, half = lane >> 5;
  float p = 0.f;
#pragma unroll
  for (int c = 0; c < 32; ++c) p += hs[wave][half * 32 + c] * w1s[j * 65 + half * 32 + c];
  p += __shfl_xor(p, 32);
  float v = elu_f(p + vb1[j]);
  if (half == 0) vs[wave][j] = v;
  __syncthreads();
  if (lane < 4 && node < n) {
    float o = vb2[lane];
#pragma unroll
    for (int jj = 0; jj < 32; ++jj) o += vs[wave][jj] * vw2[lane * 32 + jj];
    out[(size_t)node * 4 + lane] = o;
  }
}

extern "C" void kernel_launch(void* const* d_in, const int* in_sizes, int n_in,
                              void* d_out, int out_size, void* d_ws, size_t ws_size,
                              hipStream_t stream) {
  const float* x      = (const float*)d_in[0];
  const int*   esrc   = (const int*)d_in[1];
  const int*   edst   = (const int*)d_in[2];
  const float* proj_w = (const float*)d_in[3];
  const float* proj_b = (const float*)d_in[4];
  const float* w[3]   = {(const float*)d_in[5],  (const float*)d_in[11], (const float*)d_in[17]};
  const float* a_s[3] = {(const float*)d_in[6],  (const float*)d_in[12], (const float*)d_in[18]};
  const float* a_d[3] = {(const float*)d_in[7],  (const float*)d_in[13], (const float*)d_in[19]};
  const float* bb[3]  = {(const float*)d_in[8],  (const float*)d_in[14], (const float*)d_in[20]};
  const float* gg[3]  = {(const float*)d_in[9],  (const float*)d_in[15], (const float*)d_in[21]};
  const float* be[3]  = {(const float*)d_in[10], (const float*)d_in[16], (const float*)d_in[22]};
  const float* vw1 = (const float*)d_in[23];
  const float* vb1 = (const float*)d_in[24];
  const float* vw2 = (const float*)d_in[25];
  const float* vb2 = (const float*)d_in[26];
  float* outp = (float*)d_out;

  const int n = in_sizes[0] / 128;
  const int E = in_sizes[1];
  const int EE = E + n;

  // ---- workspace layout ----
  char* p = (char*)d_ws;
  auto alloc = [&](size_t bytes) { char* r = p; p += (bytes + 255) & ~(size_t)255; return r; };
  float* BIG   = (float*)alloc((size_t)n * 1024);  // rows of 1KB: bf16-A view (lda=512); final f32 [n,64]
  u16*   featB = (u16*)alloc((size_t)n * 512);     // bf16 [n,256]; first used as bf16 x [n,128]
  float* asrcN = (float*)alloc((size_t)n * 16);
  float* adstN = (float*)alloc((size_t)n * 16);
  u16* wbp = (u16*)alloc(64 * 128 * 2);
  u16* wb[3];
  wb[0] = (u16*)alloc(256 * 64 * 2);
  wb[1] = (u16*)alloc(256 * 256 * 2);
  wb[2] = (u16*)alloc(256 * 256 * 2);
  int* deg    = (int*)alloc((size_t)n * 4);
  int* rowptr = (int*)alloc((size_t)(n + 1) * 4);
  int* cursor = (int*)alloc((size_t)n * 4);
  int* col    = (int*)alloc((size_t)EE * 4);
  float* hfinal = (float*)BIG;  // layer-2 output, f32 [n,64] (BIG free after layer-2 gemm)

  // ---- CSR build ----
  hipMemsetAsync(deg, 0, (size_t)n * sizeof(int), stream);
  deg_count_k<<<(EE + 255) / 256, 256, 0, stream>>>(esrc, edst, E, n, deg);
  scan_rowptr_k<<<1, 1024, 0, stream>>>(deg, rowptr, cursor, n);
  scatter_k<<<(EE + 255) / 256, 256, 0, stream>>>(esrc, edst, E, n, cursor, col);

  // ---- dtype conversions ----
  cvt8_k<<<((size_t)n * 128 / 8 + 255) / 256, 256, 0, stream>>>(x, featB, n * 128);
  cvt_w_k<<<(64 * 128 + 255) / 256, 256, 0, stream>>>(proj_w, wbp, 64 * 128);
  cvt_w_k<<<(256 * 64 + 255) / 256, 256, 0, stream>>>(w[0], wb[0], 256 * 64);
  cvt_w_k<<<(256 * 256 + 255) / 256, 256, 0, stream>>>(w[1], wb[1], 256 * 256);
  cvt_w_k<<<(256 * 256 + 255) / 256, 256, 0, stream>>>(w[2], wb[2], 256 * 256);

  const int nb4 = (n + 3) / 4;
  const int nbg = (n + 127) / 128;
  dim3 blk(256);

  // ---- projection: BIG(bf16 rows, lda=512) = elu(x @ proj_w^T + proj_b) ----
  gemm_bf16_k<1><<<dim3(nbg, 1), blk, 0, stream>>>(featB, 128, wbp, proj_b, (u16*)BIG, 512, n, 128, 64);

  const int Kin[3] = {64, 256, 256};
  for (int i = 0; i < 3; ++i) {
    gemm_bf16_k<0><<<dim3(nbg, 2), blk, 0, stream>>>((const u16*)BIG, 512, wb[i], nullptr, featB, 256, n, Kin[i], 256);
    attn_scores_k<<<nb4, blk, 0, stream>>>(featB, a_s[i], a_d[i], asrcN, adstN, n);
    if (i < 2) {
      gat_agg_fused_k<0><<<nb4, blk, 0, stream>>>(featB, asrcN, adstN, rowptr, col,
                                                  bb[i], gg[i], be[i], (void*)BIG, n);
    } else {
      gat_agg_fused_k<1><<<nb4, blk, 0, stream>>>(featB, asrcN, adstN, rowptr, col,
                                                  bb[i], gg[i], be[i], (void*)hfinal, n);
    }
  }

  // ---- value head ----
  value_head_k<<<nb4, blk, 0, stream>>>(hfinal, vw1, vb1, vw2, vb2, outp, n);
}

// Round 4
// 473.929 us; speedup vs baseline: 2.3194x; 1.1554x over previous
//
#include <hip/hip_runtime.h>

typedef unsigned short u16;
typedef u16 u16x4 __attribute__((ext_vector_type(4)));
typedef short short8 __attribute__((ext_vector_type(8)));
typedef float f32x4 __attribute__((ext_vector_type(4)));

__device__ __forceinline__ float elu_f(float x) { return x > 0.f ? x : expm1f(x); }
__device__ __forceinline__ float lrelu_f(float x) { return x > 0.f ? x : 0.2f * x; }

__device__ __forceinline__ u16 f2b(float f) {
  union { float f; unsigned u; } v; v.f = f;
  unsigned r = v.u + 0x7FFF + ((v.u >> 16) & 1);
  return (u16)(r >> 16);
}
__device__ __forceinline__ float b2f(u16 u) {
  union { unsigned u; float f; } v; v.u = ((unsigned)u) << 16; return v.f;
}

// ---------------- CSR build ----------------
__global__ void deg_count_k(const int* __restrict__ src, const int* __restrict__ dst,
                            int E, int n, int* __restrict__ deg) {
  int e = blockIdx.x * blockDim.x + threadIdx.x;
  if (e < E) {
    atomicAdd(&deg[dst[e]], 1);
  } else if (e < E + n) {
    atomicAdd(&deg[e - E], 1);  // self loop
  }
}

// phase 1: per-block (256 elems) sums
__global__ __launch_bounds__(256) void block_sum_k(const int* __restrict__ deg,
                                                   int* __restrict__ bsum, int n) {
  int i = blockIdx.x * 256 + threadIdx.x;
  int v = (i < n) ? deg[i] : 0;
#pragma unroll
  for (int off = 1; off < 64; off <<= 1) v += __shfl_xor(v, off);
  __shared__ int ws[4];
  if ((threadIdx.x & 63) == 0) ws[threadIdx.x >> 6] = v;
  __syncthreads();
  if (threadIdx.x == 0) bsum[blockIdx.x] = ws[0] + ws[1] + ws[2] + ws[3];
}

// phase 2: single-block exclusive scan of block sums (nb <= 1024)
__global__ void scan_bsum_k(int* __restrict__ bsum, int nb) {
  __shared__ int s[1024];
  int tid = threadIdx.x;
  int v = (tid < nb) ? bsum[tid] : 0;
  s[tid] = v;
  __syncthreads();
  for (int off = 1; off < 1024; off <<= 1) {
    int t = (tid >= off) ? s[tid - off] : 0;
    __syncthreads();
    s[tid] += t;
    __syncthreads();
  }
  if (tid < nb) bsum[tid] = s[tid] - v;  // exclusive
}

// phase 3: per-block scan + offset -> rowptr, cursor
__global__ __launch_bounds__(256) void block_scan_k(const int* __restrict__ deg,
                                                    const int* __restrict__ bsum,
                                                    int* __restrict__ rowptr,
                                                    int* __restrict__ cursor, int n) {
  int i = blockIdx.x * 256 + threadIdx.x;
  int lane = threadIdx.x & 63, w = threadIdx.x >> 6;
  int v = (i < n) ? deg[i] : 0;
  int x = v;
#pragma unroll
  for (int off = 1; off < 64; off <<= 1) {
    int t = __shfl_up(x, off);
    if (lane >= off) x += t;
  }
  __shared__ int ws[4];
  if (lane == 63) ws[w] = x;
  __syncthreads();
  int add = bsum[blockIdx.x];
  for (int j = 0; j < w; ++j) add += ws[j];
  int excl = x - v + add;
  if (i < n) {
    cursor[i] = excl;
    rowptr[i + 1] = excl + v;
  }
  if (i == 0) rowptr[0] = 0;
}

__global__ void scatter_k(const int* __restrict__ src, const int* __restrict__ dst,
                          int E, int n, int* __restrict__ cursor,
                          int* __restrict__ col, int* __restrict__ dst2) {
  int e = blockIdx.x * blockDim.x + threadIdx.x;
  if (e < E) {
    int d = dst[e];
    int pos = atomicAdd(&cursor[d], 1);
    col[pos] = src[e];
    dst2[pos] = d;
  } else if (e < E + n) {
    int d = e - E;
    int pos = atomicAdd(&cursor[d], 1);
    col[pos] = d;  // self loop
    dst2[pos] = d;
  }
}

__global__ void cvt_w_k(const float* __restrict__ w, u16* __restrict__ o, int sz) {
  int i = blockIdx.x * blockDim.x + threadIdx.x;
  if (i < sz) o[i] = f2b(w[i]);
}

// vectorized f32 -> bf16, sz multiple of 8
__global__ void cvt8_k(const float* __restrict__ in, u16* __restrict__ o, int sz) {
  int i = (blockIdx.x * blockDim.x + threadIdx.x) * 8;
  if (i >= sz) return;
  float4 a = *reinterpret_cast<const float4*>(&in[i]);
  float4 b = *reinterpret_cast<const float4*>(&in[i + 4]);
  u16x4 o0, o1;
  o0.x = f2b(a.x); o0.y = f2b(a.y); o0.z = f2b(a.z); o0.w = f2b(a.w);
  o1.x = f2b(b.x); o1.y = f2b(b.y); o1.z = f2b(b.z); o1.w = f2b(b.w);
  *reinterpret_cast<u16x4*>(&o[i]) = o0;
  *reinterpret_cast<u16x4*>(&o[i + 4]) = o1;
}

// ---------------- bf16 MFMA GEMM: Cb[n,ncols](bf16,ldc) = A[n,K](bf16,lda) @ W[ncols,K]^T ----------------
template <int BIASELU>
__global__ __launch_bounds__(256) void gemm_bf16_k(const u16* __restrict__ A, int lda,
                                                   const u16* __restrict__ W,
                                                   const float* __restrict__ bias,
                                                   u16* __restrict__ Cb, int ldc,
                                                   int n, int K, int ncols) {
  __shared__ int4 Abuf[1024];  // 128 rows x 128B, XOR-swizzled
  __shared__ int4 Bbuf[1024];
  char* Asb = (char*)Abuf;
  char* Bsb = (char*)Bbuf;
  const int t = threadIdx.x;
  const int lane = t & 63, w = t >> 6;
  const int wrow = w >> 1, wcol = w & 1;
  const int row0 = blockIdx.x * 128, col0 = blockIdx.y * 128;
  f32x4 acc[4][4];
#pragma unroll
  for (int m = 0; m < 4; ++m)
#pragma unroll
    for (int nf = 0; nf < 4; ++nf) acc[m][nf] = (f32x4){0.f, 0.f, 0.f, 0.f};

  for (int k0 = 0; k0 < K; k0 += 64) {
#pragma unroll
    for (int i = 0; i < 4; ++i) {
      int ci = i * 256 + t;           // 16B chunk index, 0..1023
      int r = ci >> 3;                // row 0..127
      int b = (ci & 7) << 4;          // byte-in-row
      int sw = b ^ ((r & 7) << 4);
      int ar = row0 + r; ar = ar < n ? ar : n - 1;
      int4 av = *reinterpret_cast<const int4*>(&A[(size_t)ar * lda + k0 + (b >> 1)]);
      *reinterpret_cast<int4*>(Asb + r * 128 + sw) = av;
      int wr = col0 + r; wr = wr < ncols ? wr : ncols - 1;
      int4 wv = *reinterpret_cast<const int4*>(&W[(size_t)wr * K + k0 + (b >> 1)]);
      *reinterpret_cast<int4*>(Bsb + r * 128 + sw) = wv;
    }
    __syncthreads();
#pragma unroll
    for (int ks = 0; ks < 2; ++ks) {
      short8 af[4], bf[4];
      int kb = ks * 64 + ((lane >> 4) << 4);
#pragma unroll
      for (int m = 0; m < 4; ++m) {
        int r = wrow * 64 + m * 16 + (lane & 15);
        af[m] = *reinterpret_cast<const short8*>(Asb + r * 128 + (kb ^ ((r & 7) << 4)));
      }
#pragma unroll
      for (int nf = 0; nf < 4; ++nf) {
        int r = wcol * 64 + nf * 16 + (lane & 15);
        bf[nf] = *reinterpret_cast<const short8*>(Bsb + r * 128 + (kb ^ ((r & 7) << 4)));
      }
#pragma unroll
      for (int m = 0; m < 4; ++m)
#pragma unroll
        for (int nf = 0; nf < 4; ++nf)
          acc[m][nf] = __builtin_amdgcn_mfma_f32_16x16x32_bf16(af[m], bf[nf], acc[m][nf], 0, 0, 0);
    }
    __syncthreads();
  }
  // epilogue: C/D layout col=lane&15, row=(lane>>4)*4+j
#pragma unroll
  for (int m = 0; m < 4; ++m) {
#pragma unroll
    for (int j = 0; j < 4; ++j) {
      int rg = row0 + wrow * 64 + m * 16 + (lane >> 4) * 4 + j;
      if (rg >= n) continue;
#pragma unroll
      for (int nf = 0; nf < 4; ++nf) {
        int cg = col0 + wcol * 64 + nf * 16 + (lane & 15);
        if (cg >= ncols) continue;
        float v = acc[m][nf][j];
        if (BIASELU) v = elu_f(v + bias[cg]);
        Cb[(size_t)rg * ldc + cg] = f2b(v);
      }
    }
  }
}

// ---------------- attention scores from bf16 feat ----------------
__global__ __launch_bounds__(256) void attn_scores_k(const u16* __restrict__ feat,
                                                     const float* __restrict__ a_s,
                                                     const float* __restrict__ a_d,
                                                     float* __restrict__ asrcN,
                                                     float* __restrict__ adstN, int n) {
  int wave = threadIdx.x >> 6, lane = threadIdx.x & 63;
  int node = blockIdx.x * 4 + wave;
  if (node >= n) return;
  u16x4 f = *reinterpret_cast<const u16x4*>(&feat[(size_t)node * 256 + lane * 4]);
  float4 as = *reinterpret_cast<const float4*>(&a_s[lane * 4]);
  float4 ad = *reinterpret_cast<const float4*>(&a_d[lane * 4]);
  float fx = b2f(f.x), fy = b2f(f.y), fz = b2f(f.z), fw = b2f(f.w);
  float ps = fx * as.x + fy * as.y + fz * as.z + fw * as.w;
  float pd = fx * ad.x + fy * ad.y + fz * ad.z + fw * ad.w;
#pragma unroll
  for (int off = 1; off < 16; off <<= 1) {
    ps += __shfl_xor(ps, off);
    pd += __shfl_xor(pd, off);
  }
  if ((lane & 15) == 0) {
    int h = lane >> 4;
    asrcN[(size_t)node * 4 + h] = ps;
    adstN[(size_t)node * 4 + h] = pd;
  }
}

// ---------------- edge-parallel softmax numerators: ex[e][h] ----------------
__global__ __launch_bounds__(256) void edge_ex_k(const int* __restrict__ col,
                                                 const int* __restrict__ dst2,
                                                 const float* __restrict__ asrcN,
                                                 const float* __restrict__ adstN,
                                                 float* __restrict__ ex, int EE) {
  int t = blockIdx.x * 256 + threadIdx.x;  // one per (e,h)
  if (t >= EE * 4) return;
  int e = t >> 2, h = t & 3;
  int s = col[e], d = dst2[e];
  float a = asrcN[(size_t)s * 4 + h] + adstN[(size_t)d * 4 + h];
  ex[t] = __expf(lrelu_f(a));  // softmax shift-invariant; |a| <~ 5 so no overflow
}

// ---------------- fused GAT aggregation + bias + LayerNorm + ELU ----------------
// MODE 0: LN(256) -> bf16 row written at (u16*)out + node*256 (packed [n,256])
// MODE 1: head-mean -> bias -> LN(64) -> ELU -> f32 out[node*64..]
template <int MODE>
__global__ __launch_bounds__(256) void gat_agg2_k(const u16* __restrict__ feat,
                                                  const float* __restrict__ ex,
                                                  const int* __restrict__ rowptr,
                                                  const int* __restrict__ col,
                                                  const float* __restrict__ bias,
                                                  const float* __restrict__ g,
                                                  const float* __restrict__ be,
                                                  void* __restrict__ out, int n) {
  int wave = threadIdx.x >> 6, lane = threadIdx.x & 63;
  int node = blockIdx.x * 4 + wave;
  if (node >= n) return;
  int h = lane >> 4;
  int s0 = rowptr[node], s1 = rowptr[node + 1];
  float ax = 0.f, ay = 0.f, az = 0.f, aw = 0.f, den = 0.f;
  int e = s0;
  for (; e + 4 <= s1; e += 4) {
    int sa = col[e + 0], sb = col[e + 1], sc = col[e + 2], sd = col[e + 3];
    float xa = ex[(size_t)(e + 0) * 4 + h];
    float xb = ex[(size_t)(e + 1) * 4 + h];
    float xc = ex[(size_t)(e + 2) * 4 + h];
    float xd = ex[(size_t)(e + 3) * 4 + h];
    u16x4 fa = *reinterpret_cast<const u16x4*>(&feat[(size_t)sa * 256 + lane * 4]);
    u16x4 fb = *reinterpret_cast<const u16x4*>(&feat[(size_t)sb * 256 + lane * 4]);
    u16x4 fc = *reinterpret_cast<const u16x4*>(&feat[(size_t)sc * 256 + lane * 4]);
    u16x4 fd = *reinterpret_cast<const u16x4*>(&feat[(size_t)sd * 256 + lane * 4]);
    den += (xa + xb) + (xc + xd);
    ax += xa * b2f(fa.x) + xb * b2f(fb.x) + xc * b2f(fc.x) + xd * b2f(fd.x);
    ay += xa * b2f(fa.y) + xb * b2f(fb.y) + xc * b2f(fc.y) + xd * b2f(fd.y);
    az += xa * b2f(fa.z) + xb * b2f(fb.z) + xc * b2f(fc.z) + xd * b2f(fd.z);
    aw += xa * b2f(fa.w) + xb * b2f(fb.w) + xc * b2f(fc.w) + xd * b2f(fd.w);
  }
  for (; e < s1; ++e) {
    int s = col[e];
    float x = ex[(size_t)e * 4 + h];
    den += x;
    u16x4 f = *reinterpret_cast<const u16x4*>(&feat[(size_t)s * 256 + lane * 4]);
    ax += x * b2f(f.x); ay += x * b2f(f.y); az += x * b2f(f.z); aw += x * b2f(f.w);
  }
  float inv = 1.f / den;  // self-loop guarantees den > 0
  ax *= inv; ay *= inv; az *= inv; aw *= inv;

  if (MODE == 0) {
    float4 b4 = *reinterpret_cast<const float4*>(&bias[lane * 4]);
    float vx = ax + b4.x, vy = ay + b4.y, vz = az + b4.z, vw = aw + b4.w;
    float s = vx + vy + vz + vw;
#pragma unroll
    for (int off = 1; off < 64; off <<= 1) s += __shfl_xor(s, off);
    float mu = s * (1.f / 256.f);
    float dx = vx - mu, dy = vy - mu, dz = vz - mu, dw = vw - mu;
    float q = dx * dx + dy * dy + dz * dz + dw * dw;
#pragma unroll
    for (int off = 1; off < 64; off <<= 1) q += __shfl_xor(q, off);
    float inv2 = rsqrtf(q * (1.f / 256.f) + 1e-5f);
    float4 gg = *reinterpret_cast<const float4*>(&g[lane * 4]);
    float4 bb = *reinterpret_cast<const float4*>(&be[lane * 4]);
    u16x4 o;
    o.x = f2b(elu_f(dx * inv2 * gg.x + bb.x));
    o.y = f2b(elu_f(dy * inv2 * gg.y + bb.y));
    o.z = f2b(elu_f(dz * inv2 * gg.z + bb.z));
    o.w = f2b(elu_f(dw * inv2 * gg.w + bb.w));
    u16* rowb = (u16*)out + (size_t)node * 256;
    *reinterpret_cast<u16x4*>(&rowb[lane * 4]) = o;
  } else {
    // head-mean: sum over h (lane bits 4,5)
    ax += __shfl_xor(ax, 16); ax += __shfl_xor(ax, 32);
    ay += __shfl_xor(ay, 16); ay += __shfl_xor(ay, 32);
    az += __shfl_xor(az, 16); az += __shfl_xor(az, 32);
    aw += __shfl_xor(aw, 16); aw += __shfl_xor(aw, 32);
    int qd = lane & 15;
    float4 b4 = *reinterpret_cast<const float4*>(&bias[qd * 4]);
    float vx = 0.25f * ax + b4.x, vy = 0.25f * ay + b4.y;
    float vz = 0.25f * az + b4.z, vw = 0.25f * aw + b4.w;
    // LN over 64 cols; each col replicated 4x across lanes -> divide by 256
    float s = vx + vy + vz + vw;
#pragma unroll
    for (int off = 1; off < 64; off <<= 1) s += __shfl_xor(s, off);
    float mu = s * (1.f / 256.f);
    float dx = vx - mu, dy = vy - mu, dz = vz - mu, dw = vw - mu;
    float q = dx * dx + dy * dy + dz * dz + dw * dw;
#pragma unroll
    for (int off = 1; off < 64; off <<= 1) q += __shfl_xor(q, off);
    float inv2 = rsqrtf(q * (1.f / 256.f) + 1e-5f);
    if (lane < 16) {
      float4 gg = *reinterpret_cast<const float4*>(&g[qd * 4]);
      float4 bb = *reinterpret_cast<const float4*>(&be[qd * 4]);
      float4 o;
      o.x = elu_f(dx * inv2 * gg.x + bb.x);
      o.y = elu_f(dy * inv2 * gg.y + bb.y);
      o.z = elu_f(dz * inv2 * gg.z + bb.z);
      o.w = elu_f(dw * inv2 * gg.w + bb.w);
      *reinterpret_cast<float4*>(&((float*)out)[(size_t)node * 64 + qd * 4]) = o;
    }
  }
}

// ---------------- value head: out[n,4] ----------------
__global__ __launch_bounds__(256) void value_head_k(const float* __restrict__ hh,
                                                    const float* __restrict__ vw1,
                                                    const float* __restrict__ vb1,
                                                    const float* __restrict__ vw2,
                                                    const float* __restrict__ vb2,
                                                    float* __restrict__ out, int n) {
  __shared__ float w1s[32 * 65];
  __shared__ float hs[4][64];
  __shared__ float vs[4][33];
  int tid = threadIdx.x;
  for (int i = tid; i < 2048; i += 256) w1s[(i >> 6) * 65 + (i & 63)] = vw1[i];
  int wave = tid >> 6, lane = tid & 63;
  int node = blockIdx.x * 4 + wave;
  int nc = node < n ? node : n - 1;
  hs[wave][lane] = hh[(size_t)nc * 64 + lane];
  __syncthreads();
  int j = lane & 31, half = lane >> 5;
  float p = 0.f;
#pragma unroll
  for (int c = 0; c < 32; ++c) p += hs[wave][half * 32 + c] * w1s[j * 65 + half * 32 + c];
  p += __shfl_xor(p, 32);
  float v = elu_f(p + vb1[j]);
  if (half == 0) vs[wave][j] = v;
  __syncthreads();
  if (lane < 4 && node < n) {
    float o = vb2[lane];
#pragma unroll
    for (int jj = 0; jj < 32; ++jj) o += vs[wave][jj] * vw2[lane * 32 + jj];
    out[(size_t)node * 4 + lane] = o;
  }
}

extern "C" void kernel_launch(void* const* d_in, const int* in_sizes, int n_in,
                              void* d_out, int out_size, void* d_ws, size_t ws_size,
                              hipStream_t stream) {
  const float* x      = (const float*)d_in[0];
  const int*   esrc   = (const int*)d_in[1];
  const int*   edst   = (const int*)d_in[2];
  const float* proj_w = (const float*)d_in[3];
  const float* proj_b = (const float*)d_in[4];
  const float* w[3]   = {(const float*)d_in[5],  (const float*)d_in[11], (const float*)d_in[17]};
  const float* a_s[3] = {(const float*)d_in[6],  (const float*)d_in[12], (const float*)d_in[18]};
  const float* a_d[3] = {(const float*)d_in[7],  (const float*)d_in[13], (const float*)d_in[19]};
  const float* bb[3]  = {(const float*)d_in[8],  (const float*)d_in[14], (const float*)d_in[20]};
  const float* gg[3]  = {(const float*)d_in[9],  (const float*)d_in[15], (const float*)d_in[21]};
  const float* be[3]  = {(const float*)d_in[10], (const float*)d_in[16], (const float*)d_in[22]};
  const float* vw1 = (const float*)d_in[23];
  const float* vb1 = (const float*)d_in[24];
  const float* vw2 = (const float*)d_in[25];
  const float* vb2 = (const float*)d_in[26];
  float* outp = (float*)d_out;

  const int n = in_sizes[0] / 128;
  const int E = in_sizes[1];
  const int EE = E + n;
  const int nbl = (n + 255) / 256;  // scan blocks (<=1024 supported)

  // ---- workspace layout ----
  char* p = (char*)d_ws;
  auto alloc = [&](size_t bytes) { char* r = p; p += (bytes + 255) & ~(size_t)255; return r; };
  u16*   hA    = (u16*)alloc((size_t)n * 512);     // packed bf16 [n,256] layer input; x bf16 first; hfinal f32 later
  u16*   featB = (u16*)alloc((size_t)n * 512);     // bf16 [n,256] gemm output
  float* ex    = (float*)alloc((size_t)EE * 16);   // softmax numerators [EE,4]
  float* asrcN = (float*)alloc((size_t)n * 16);
  float* adstN = (float*)alloc((size_t)n * 16);
  u16* wbp = (u16*)alloc(64 * 128 * 2);
  u16* wb[3];
  wb[0] = (u16*)alloc(256 * 64 * 2);
  wb[1] = (u16*)alloc(256 * 256 * 2);
  wb[2] = (u16*)alloc(256 * 256 * 2);
  int* deg    = (int*)alloc((size_t)n * 4);
  int* rowptr = (int*)alloc((size_t)(n + 1) * 4);
  int* cursor = (int*)alloc((size_t)n * 4);
  int* col    = (int*)alloc((size_t)EE * 4);
  int* dst2   = (int*)alloc((size_t)EE * 4);
  int* bsum   = (int*)alloc((size_t)nbl * 4);
  float* hfinal = (float*)hA;  // f32 [n,64]; hA dead after layer-2 gemm

  // ---- CSR build ----
  hipMemsetAsync(deg, 0, (size_t)n * sizeof(int), stream);
  deg_count_k<<<(EE + 255) / 256, 256, 0, stream>>>(esrc, edst, E, n, deg);
  block_sum_k<<<nbl, 256, 0, stream>>>(deg, bsum, n);
  scan_bsum_k<<<1, 1024, 0, stream>>>(bsum, nbl);
  block_scan_k<<<nbl, 256, 0, stream>>>(deg, bsum, rowptr, cursor, n);
  scatter_k<<<(EE + 255) / 256, 256, 0, stream>>>(esrc, edst, E, n, cursor, col, dst2);

  // ---- dtype conversions ----
  cvt8_k<<<((size_t)n * 128 / 8 + 255) / 256, 256, 0, stream>>>(x, featB, n * 128);
  cvt_w_k<<<(64 * 128 + 255) / 256, 256, 0, stream>>>(proj_w, wbp, 64 * 128);
  cvt_w_k<<<(256 * 64 + 255) / 256, 256, 0, stream>>>(w[0], wb[0], 256 * 64);
  cvt_w_k<<<(256 * 256 + 255) / 256, 256, 0, stream>>>(w[1], wb[1], 256 * 256);
  cvt_w_k<<<(256 * 256 + 255) / 256, 256, 0, stream>>>(w[2], wb[2], 256 * 256);

  const int nb4 = (n + 3) / 4;
  const int nbg = (n + 127) / 128;
  dim3 blk(256);

  // ---- projection: hA[n,0..63] = elu(x @ proj_w^T + proj_b), bf16, ldc=256 ----
  gemm_bf16_k<1><<<dim3(nbg, 1), blk, 0, stream>>>(featB, 128, wbp, proj_b, hA, 256, n, 128, 64);

  const int Kin[3] = {64, 256, 256};
  for (int i = 0; i < 3; ++i) {
    gemm_bf16_k<0><<<dim3(nbg, 2), blk, 0, stream>>>(hA, 256, wb[i], nullptr, featB, 256, n, Kin[i], 256);
    attn_scores_k<<<nb4, blk, 0, stream>>>(featB, a_s[i], a_d[i], asrcN, adstN, n);
    edge_ex_k<<<((size_t)EE * 4 + 255) / 256, 256, 0, stream>>>(col, dst2, asrcN, adstN, ex, EE);
    if (i < 2) {
      gat_agg2_k<0><<<nb4, blk, 0, stream>>>(featB, ex, rowptr, col, bb[i], gg[i], be[i], (void*)hA, n);
    } else {
      gat_agg2_k<1><<<nb4, blk, 0, stream>>>(featB, ex, rowptr, col, bb[i], gg[i], be[i], (void*)hfinal, n);
    }
  }

  // ---- value head ----
  value_head_k<<<nb4, blk, 0, stream>>>(hfinal, vw1, vb1, vw2, vb2, outp, n);
}